// Round 1
// baseline (1030.153 us; speedup 1.0000x reference)
//
#include <hip/hip_runtime.h>
#include <hip/hip_fp16.h>

#define SS 2048
#define HH 30
#define KVHH 6
#define DD 64
#define HIDD 1920
#define NQKV 2688   // 1920 (q) + 384 (k) + 384 (v)

typedef __attribute__((ext_vector_type(4))) float  f32x4;
typedef __attribute__((ext_vector_type(4))) float  float4v;
typedef __attribute__((ext_vector_type(8))) _Float16 f16x8;
typedef __attribute__((ext_vector_type(4))) _Float16 f16x4;

// ---------------------------------------------------------------- cvt f32->f16 (*alpha)
__global__ __launch_bounds__(256) void cvt_f16(const float* __restrict__ in,
                                               _Float16* __restrict__ out,
                                               const float* __restrict__ alpha, int n) {
    int i = (blockIdx.x * 256 + threadIdx.x) * 4;
    if (i >= n) return;
    float a = alpha ? alpha[0] : 1.0f;
    float4v v = *(const float4v*)(in + i);
    f16x4 o;
    o[0] = (_Float16)(v[0] * a);
    o[1] = (_Float16)(v[1] * a);
    o[2] = (_Float16)(v[2] * a);
    o[3] = (_Float16)(v[3] * a);
    *(f16x4*)(out + i) = o;
}

// ---------------------------------------------------------------- GEMM: C[M][N] = A[M][K] * B[N][K]^T
// A,B fp16 row-major (K inner). 128x128 tile, BK=64, 256 thr (4 waves, 2x2 of 64x64).
// LDS slots XOR-swizzled: phys slot = logical slot ^ (row&7)  (conflict-free b128 reads,
// inverse applied on the global source of global_load_lds per guide rule 21).
__global__ __launch_bounds__(256) void gemm_bt_f16(const _Float16* __restrict__ A,
                                                   const _Float16* __restrict__ B,
                                                   float* __restrict__ C,
                                                   int M, int N, int K) {
    __shared__ __align__(16) _Float16 As[128 * 64];
    __shared__ __align__(16) _Float16 Bs[128 * 64];
    const int tid = threadIdx.x;
    const int l   = tid & 63;
    const int w   = tid >> 6;
    const int wm  = (w >> 1) * 64;
    const int wn  = (w & 1) * 64;
    const int m0  = blockIdx.y * 128;
    const int n0  = blockIdx.x * 128;

    f32x4 acc[4][4];
#pragma unroll
    for (int a = 0; a < 4; ++a)
#pragma unroll
        for (int b = 0; b < 4; ++b) acc[a][b] = (f32x4)0.0f;

    for (int kt = 0; kt < K; kt += 64) {
#pragma unroll
        for (int it = 0; it < 4; ++it) {
            int g = it * 256 + tid;            // 0..1023, lane-linear per wave
            int row = g >> 3;
            int s   = (g & 7) ^ (row & 7);     // pre-swizzled global source slot
            const _Float16* gA = A + (size_t)(m0 + row) * K + kt + s * 8;
            const _Float16* gB = B + (size_t)(n0 + row) * K + kt + s * 8;
            _Float16* lA = As + (size_t)(it * 256 + w * 64) * 8;   // wave-uniform base
            _Float16* lB = Bs + (size_t)(it * 256 + w * 64) * 8;
            __builtin_amdgcn_global_load_lds((const __attribute__((address_space(1))) unsigned int*)gA,
                                             (__attribute__((address_space(3))) unsigned int*)lA, 16, 0, 0);
            __builtin_amdgcn_global_load_lds((const __attribute__((address_space(1))) unsigned int*)gB,
                                             (__attribute__((address_space(3))) unsigned int*)lB, 16, 0, 0);
        }
        __syncthreads();   // drains vmcnt+lgkmcnt

#pragma unroll
        for (int kk = 0; kk < 2; ++kk) {
            f16x8 af[4], bf[4];
#pragma unroll
            for (int fm = 0; fm < 4; ++fm) {
                int row = wm + fm * 16 + (l & 15);
                int s   = (kk * 4 + (l >> 4)) ^ (row & 7);
                af[fm] = *(const f16x8*)(As + row * 64 + s * 8);
            }
#pragma unroll
            for (int fn = 0; fn < 4; ++fn) {
                int row = wn + fn * 16 + (l & 15);
                int s   = (kk * 4 + (l >> 4)) ^ (row & 7);
                bf[fn] = *(const f16x8*)(Bs + row * 64 + s * 8);
            }
#pragma unroll
            for (int fm = 0; fm < 4; ++fm)
#pragma unroll
                for (int fn = 0; fn < 4; ++fn)
                    acc[fm][fn] = __builtin_amdgcn_mfma_f32_16x16x32_f16(af[fm], bf[fn], acc[fm][fn], 0, 0, 0);
        }
        __syncthreads();
    }

    // C/D layout: col = lane&15, row = (lane>>4)*4 + reg
#pragma unroll
    for (int fm = 0; fm < 4; ++fm)
#pragma unroll
        for (int fn = 0; fn < 4; ++fn)
#pragma unroll
            for (int j = 0; j < 4; ++j) {
                int r = m0 + wm + fm * 16 + (l >> 4) * 4 + j;
                int c = n0 + wn + fn * 16 + (l & 15);
                C[(size_t)r * N + c] = acc[fm][fn][j];
            }
}

// ---------------------------------------------------------------- per-head LN + RoPE + reformat
// one wave per (s, unit); unit<30: Q head, 30..35: K head, 36..41: V head
__global__ __launch_bounds__(256) void lnrope(const float* __restrict__ qkv,
                                              const float* __restrict__ qlnw,
                                              const float* __restrict__ klnw,
                                              _Float16* __restrict__ Qh,
                                              _Float16* __restrict__ Kh,
                                              _Float16* __restrict__ Vh) {
    int task = blockIdx.x * 4 + (threadIdx.x >> 6);
    int lane = threadIdx.x & 63;
    int s = task / 42;
    int u = task % 42;
    if (s >= SS) return;

    if (u < 36) {   // Q or K: LayerNorm + RoPE
        int head  = (u < 30) ? u : (u - 30);
        int col   = (u < 30) ? (u * 64 + lane) : (1920 + head * 64 + lane);
        const float* lw = (u < 30) ? qlnw : klnw;
        float x = qkv[(size_t)s * NQKV + col];

        float mu = x;
#pragma unroll
        for (int off = 32; off; off >>= 1) mu += __shfl_xor(mu, off);
        mu *= (1.0f / 64.0f);
        float d = x - mu;
        float var = d * d;
#pragma unroll
        for (int off = 32; off; off >>= 1) var += __shfl_xor(var, off);
        var *= (1.0f / 64.0f);
        float xn = d * rsqrtf(var + 1e-5f) * lw[head * 64 + lane];

        // RoPE: inv_freq = 10000^{-(lane&31)/32}
        float f = exp2f(-13.287712379549449f * (float)(lane & 31) * (1.0f / 32.0f));
        float ang = (float)s * f;
        float sn, cs;
        sincosf(ang, &sn, &cs);
        float prt = __shfl_xor(xn, 32);
        float rot = (lane < 32) ? -prt : prt;
        float r = xn * cs + rot * sn;

        if (u < 30) Qh[((size_t)head * SS + s) * 64 + lane] = (_Float16)r;
        else        Kh[((size_t)head * SS + s) * 64 + lane] = (_Float16)r;
    } else {        // V: passthrough (v_alpha already folded into Wv)
        int head = u - 36;
        float x = qkv[(size_t)s * NQKV + 2304 + head * 64 + lane];
        Vh[((size_t)head * SS + s) * 64 + lane] = (_Float16)x;
    }
}

// ---------------------------------------------------------------- sliding-window flash attention (fp32 VALU)
// grid (32 qblocks, 30 heads), 512 thr = 8 waves, each wave owns 8 q-rows.
__global__ __launch_bounds__(512) void attn(const _Float16* __restrict__ Qh,
                                            const _Float16* __restrict__ Kh,
                                            const _Float16* __restrict__ Vh,
                                            _Float16* __restrict__ Ob) {
    __shared__ float Qs[64][64];   // [r][d], reads are wave-uniform broadcast
    __shared__ float Kt[64][65];   // [d][j], +1 pad: conflict-free transposed writes
    __shared__ float Vs[64][64];   // [j][d]
    __shared__ float Pl[8][64];    // per-wave p row

    const int qb = blockIdx.x, h = blockIdx.y;
    const int Q0 = qb * 64;
    const int kvh = h / 5;
    const int tid = threadIdx.x, lane = tid & 63, w = tid >> 6;

    for (int idx = tid; idx < 4096; idx += 512) {
        int r = idx >> 6, d = idx & 63;
        Qs[r][d] = (float)Qh[((size_t)h * SS + Q0 + r) * 64 + d] * 0.125f;  // 1/sqrt(64)
    }

    float m_i[8], l_i[8], o_i[8];
#pragma unroll
    for (int ri = 0; ri < 8; ++ri) { m_i[ri] = -1e30f; l_i[ri] = 0.0f; o_i[ri] = 0.0f; }

    const int c_lo = (Q0 >= 1023) ? ((Q0 - 1023) >> 6) : 0;
    const int c_hi = qb;

    for (int c = c_lo; c <= c_hi; ++c) {
        __syncthreads();
        for (int idx = tid; idx < 4096; idx += 512) {
            int j = idx >> 6, d = idx & 63;
            float kv = (float)Kh[((size_t)kvh * SS + c * 64 + j) * 64 + d];
            float vv = (float)Vh[((size_t)kvh * SS + c * 64 + j) * 64 + d];
            Kt[d][j] = kv;
            Vs[j][d] = vv;
        }
        __syncthreads();

        const int jbase = c * 64;
#pragma unroll
        for (int ri = 0; ri < 8; ++ri) {
            const int r = w * 8 + ri;
            const int i = Q0 + r;
            if (jbase > i || jbase + 63 < i - 1023) continue;   // chunk fully masked for this row

            const int jj = jbase + lane;
            const bool valid = (jj <= i) && (jj >= i - 1023);
            float sc = 0.0f;
#pragma unroll
            for (int d = 0; d < 64; ++d) sc += Qs[r][d] * Kt[d][lane];
            if (!valid) sc = -1e30f;

            float mx = sc;
#pragma unroll
            for (int off = 32; off; off >>= 1) mx = fmaxf(mx, __shfl_xor(mx, off));
            float m_new = fmaxf(m_i[ri], mx);
            float p = valid ? __expf(sc - m_new) : 0.0f;
            float ps = p;
#pragma unroll
            for (int off = 32; off; off >>= 1) ps += __shfl_xor(ps, off);
            float corr = __expf(m_i[ri] - m_new);
            l_i[ri] = l_i[ri] * corr + ps;
            m_i[ri] = m_new;
            Pl[w][lane] = p;

            float acc = o_i[ri] * corr;
#pragma unroll
            for (int j2 = 0; j2 < 64; ++j2) acc += Pl[w][j2] * Vs[j2][lane];
            o_i[ri] = acc;
        }
    }

#pragma unroll
    for (int ri = 0; ri < 8; ++ri) {
        int r = w * 8 + ri;
        float o = o_i[ri] / l_i[ri];
        Ob[(size_t)(Q0 + r) * HIDD + h * 64 + lane] = (_Float16)o;
    }
}

// ---------------------------------------------------------------- launch
extern "C" void kernel_launch(void* const* d_in, const int* in_sizes, int n_in,
                              void* d_out, int out_size, void* d_ws, size_t ws_size,
                              hipStream_t stream) {
    const float* hs   = (const float*)d_in[0];
    // d_in[1] = position_ids (arange, unused — positions derived from row index)
    const float* Wq   = (const float*)d_in[2];
    const float* Wk   = (const float*)d_in[3];
    const float* Wv   = (const float*)d_in[4];
    const float* Wo   = (const float*)d_in[5];
    const float* qlnw = (const float*)d_in[6];
    const float* klnw = (const float*)d_in[7];
    const float* qa   = (const float*)d_in[8];
    const float* ka   = (const float*)d_in[9];
    const float* va   = (const float*)d_in[10];
    const float* oa   = (const float*)d_in[11];

    char* ws = (char*)d_ws;
    _Float16* hsb   = (_Float16*)ws;                 ws += (size_t)SS * HIDD * 2;        // 7.86 MB
    _Float16* wqkvb = (_Float16*)ws;                 ws += (size_t)NQKV * HIDD * 2;      // 10.3 MB
    _Float16* wob   = (_Float16*)ws;                 ws += (size_t)HIDD * HIDD * 2;      // 7.37 MB
    float*    qkv   = (float*)ws;                    ws += (size_t)SS * NQKV * 4;        // 22.0 MB
    _Float16* Qhd   = (_Float16*)ws;                 ws += (size_t)HH * SS * DD * 2;     // 7.86 MB
    _Float16* Khd   = (_Float16*)ws;                 ws += (size_t)KVHH * SS * DD * 2;   // 1.57 MB
    _Float16* Vhd   = (_Float16*)ws;                 ws += (size_t)KVHH * SS * DD * 2;   // 1.57 MB
    _Float16* attnb = (_Float16*)ws;                 ws += (size_t)SS * HIDD * 2;        // 7.86 MB

    // fp32 -> fp16 with alpha folded into the weights
    cvt_f16<<<3840, 256, 0, stream>>>(hs, hsb, nullptr, SS * HIDD);
    cvt_f16<<<3600, 256, 0, stream>>>(Wq, wqkvb, qa, HIDD * HIDD);
    cvt_f16<<<720,  256, 0, stream>>>(Wk, wqkvb + (size_t)1920 * HIDD, ka, 384 * HIDD);
    cvt_f16<<<720,  256, 0, stream>>>(Wv, wqkvb + (size_t)2304 * HIDD, va, 384 * HIDD);
    cvt_f16<<<3600, 256, 0, stream>>>(Wo, wob, oa, HIDD * HIDD);

    // fused QKV projection: [2048,2688] = hs[2048,1920] @ Wqkv[2688,1920]^T
    gemm_bt_f16<<<dim3(NQKV / 128, SS / 128), 256, 0, stream>>>(hsb, wqkvb, qkv, SS, NQKV, HIDD);

    // per-head LN + RoPE + head-major reformat
    lnrope<<<(SS * 42) / 4, 256, 0, stream>>>(qkv, qlnw, klnw, Qhd, Khd, Vhd);

    // sliding-window attention
    attn<<<dim3(SS / 64, HH), 512, 0, stream>>>(Qhd, Khd, Vhd, attnb);

    // output projection: [2048,1920] = attnb @ Wo[1920,1920]^T
    gemm_bt_f16<<<dim3(HIDD / 128, SS / 128), 256, 0, stream>>>(attnb, wob, (float*)d_out, SS, HIDD, HIDD);
}

// Round 2
// 172.868 us; speedup vs baseline: 5.9592x; 5.9592x over previous
//
#include <hip/hip_runtime.h>
#include <hip/hip_fp16.h>

#define SS 2048
#define HH 30
#define KVHH 6
#define DD 64
#define HIDD 1920
#define NQKV 2688   // 1920 (q) + 384 (k) + 384 (v)

typedef __attribute__((ext_vector_type(4))) float  f32x4;
typedef __attribute__((ext_vector_type(4))) float  float4v;
typedef __attribute__((ext_vector_type(8))) _Float16 f16x8;
typedef __attribute__((ext_vector_type(4))) _Float16 f16x4;

// ---------------------------------------------------------------- cvt f32->f16 (*alpha)
__global__ __launch_bounds__(256) void cvt_f16(const float* __restrict__ in,
                                               _Float16* __restrict__ out,
                                               const float* __restrict__ alpha, int n) {
    int i = (blockIdx.x * 256 + threadIdx.x) * 4;
    if (i >= n) return;
    float a = alpha ? alpha[0] : 1.0f;
    float4v v = *(const float4v*)(in + i);
    f16x4 o;
    o[0] = (_Float16)(v[0] * a);
    o[1] = (_Float16)(v[1] * a);
    o[2] = (_Float16)(v[2] * a);
    o[3] = (_Float16)(v[3] * a);
    *(f16x4*)(out + i) = o;
}

// ---------------------------------------------------------------- GEMM: C[M][N] = A[M][K] * B[N][K]^T
__global__ __launch_bounds__(256) void gemm_bt_f16(const _Float16* __restrict__ A,
                                                   const _Float16* __restrict__ B,
                                                   float* __restrict__ C,
                                                   int M, int N, int K) {
    __shared__ __align__(16) _Float16 As[128 * 64];
    __shared__ __align__(16) _Float16 Bs[128 * 64];
    const int tid = threadIdx.x;
    const int l   = tid & 63;
    const int w   = tid >> 6;
    const int wm  = (w >> 1) * 64;
    const int wn  = (w & 1) * 64;
    const int m0  = blockIdx.y * 128;
    const int n0  = blockIdx.x * 128;

    f32x4 acc[4][4];
#pragma unroll
    for (int a = 0; a < 4; ++a)
#pragma unroll
        for (int b = 0; b < 4; ++b) acc[a][b] = (f32x4)0.0f;

    for (int kt = 0; kt < K; kt += 64) {
#pragma unroll
        for (int it = 0; it < 4; ++it) {
            int g = it * 256 + tid;
            int row = g >> 3;
            int s   = (g & 7) ^ (row & 7);
            const _Float16* gA = A + (size_t)(m0 + row) * K + kt + s * 8;
            const _Float16* gB = B + (size_t)(n0 + row) * K + kt + s * 8;
            _Float16* lA = As + (size_t)(it * 256 + w * 64) * 8;
            _Float16* lB = Bs + (size_t)(it * 256 + w * 64) * 8;
            __builtin_amdgcn_global_load_lds((const __attribute__((address_space(1))) unsigned int*)gA,
                                             (__attribute__((address_space(3))) unsigned int*)lA, 16, 0, 0);
            __builtin_amdgcn_global_load_lds((const __attribute__((address_space(1))) unsigned int*)gB,
                                             (__attribute__((address_space(3))) unsigned int*)lB, 16, 0, 0);
        }
        __syncthreads();

#pragma unroll
        for (int kk = 0; kk < 2; ++kk) {
            f16x8 af[4], bf[4];
#pragma unroll
            for (int fm = 0; fm < 4; ++fm) {
                int row = wm + fm * 16 + (l & 15);
                int s   = (kk * 4 + (l >> 4)) ^ (row & 7);
                af[fm] = *(const f16x8*)(As + row * 64 + s * 8);
            }
#pragma unroll
            for (int fn = 0; fn < 4; ++fn) {
                int row = wn + fn * 16 + (l & 15);
                int s   = (kk * 4 + (l >> 4)) ^ (row & 7);
                bf[fn] = *(const f16x8*)(Bs + row * 64 + s * 8);
            }
#pragma unroll
            for (int fm = 0; fm < 4; ++fm)
#pragma unroll
                for (int fn = 0; fn < 4; ++fn)
                    acc[fm][fn] = __builtin_amdgcn_mfma_f32_16x16x32_f16(af[fm], bf[fn], acc[fm][fn], 0, 0, 0);
        }
        __syncthreads();
    }

#pragma unroll
    for (int fm = 0; fm < 4; ++fm)
#pragma unroll
        for (int fn = 0; fn < 4; ++fn)
#pragma unroll
            for (int j = 0; j < 4; ++j) {
                int r = m0 + wm + fm * 16 + (l >> 4) * 4 + j;
                int c = n0 + wn + fn * 16 + (l & 15);
                C[(size_t)r * N + c] = acc[fm][fn][j];
            }
}

// ---------------------------------------------------------------- per-head LN + RoPE + reformat
// Q written pre-scaled by 1/sqrt(D) = 0.125
__global__ __launch_bounds__(256) void lnrope(const float* __restrict__ qkv,
                                              const float* __restrict__ qlnw,
                                              const float* __restrict__ klnw,
                                              _Float16* __restrict__ Qh,
                                              _Float16* __restrict__ Kh,
                                              _Float16* __restrict__ Vh) {
    int task = blockIdx.x * 4 + (threadIdx.x >> 6);
    int lane = threadIdx.x & 63;
    int s = task / 42;
    int u = task % 42;
    if (s >= SS) return;

    if (u < 36) {
        int head  = (u < 30) ? u : (u - 30);
        int col   = (u < 30) ? (u * 64 + lane) : (1920 + head * 64 + lane);
        const float* lw = (u < 30) ? qlnw : klnw;
        float x = qkv[(size_t)s * NQKV + col];

        float mu = x;
#pragma unroll
        for (int off = 32; off; off >>= 1) mu += __shfl_xor(mu, off);
        mu *= (1.0f / 64.0f);
        float d = x - mu;
        float var = d * d;
#pragma unroll
        for (int off = 32; off; off >>= 1) var += __shfl_xor(var, off);
        var *= (1.0f / 64.0f);
        float xn = d * rsqrtf(var + 1e-5f) * lw[head * 64 + lane];

        float f = exp2f(-13.287712379549449f * (float)(lane & 31) * (1.0f / 32.0f));
        float ang = (float)s * f;
        float sn, cs;
        sincosf(ang, &sn, &cs);
        float prt = __shfl_xor(xn, 32);
        float rot = (lane < 32) ? -prt : prt;
        float r = xn * cs + rot * sn;

        if (u < 30) Qh[((size_t)head * SS + s) * 64 + lane] = (_Float16)(r * 0.125f);
        else        Kh[((size_t)head * SS + s) * 64 + lane] = (_Float16)r;
    } else {
        int head = u - 36;
        float x = qkv[(size_t)s * NQKV + 2304 + head * 64 + lane];
        Vh[((size_t)head * SS + s) * 64 + lane] = (_Float16)x;
    }
}

// ---------------------------------------------------------------- V transpose: Vh[h][s][d] -> Vt[h][d][s]
__global__ __launch_bounds__(256) void transpose_v(const _Float16* __restrict__ Vh,
                                                   _Float16* __restrict__ Vt) {
    __shared__ _Float16 T[64][68];
    const int s0 = blockIdx.x * 64;
    const int h  = blockIdx.y;
    const int tid = threadIdx.x;
#pragma unroll
    for (int pass = 0; pass < 2; ++pass) {
        int idx = pass * 256 + tid;
        int r = idx >> 3, d0 = (idx & 7) * 8;
        f16x8 v = *(const f16x8*)(Vh + ((size_t)(h * SS + s0 + r)) * 64 + d0);
#pragma unroll
        for (int j = 0; j < 8; ++j) T[r][d0 + j] = v[j];
    }
    __syncthreads();
#pragma unroll
    for (int pass = 0; pass < 2; ++pass) {
        int idx = pass * 256 + tid;
        int d = idx >> 3, c0 = (idx & 7) * 8;
        f16x8 o;
#pragma unroll
        for (int j = 0; j < 8; ++j) o[j] = T[c0 + j][d];
        *(f16x8*)(Vt + ((size_t)(h * 64 + d)) * SS + s0 + c0) = o;
    }
}

// ---------------------------------------------------------------- MFMA sliding-window attention
// block = (qblock of 64 rows, head). 256 thr = 4 waves, wave w owns q rows w*16..w*16+15.
// Swapped QK^T (S^T = mfma(K,Q)): softmax row (fixed q) = lane&15 -> reduce via shfl_xor(16,32).
__global__ __launch_bounds__(256) void attn_mfma(const _Float16* __restrict__ Qh,
                                                 const _Float16* __restrict__ Kh,
                                                 const _Float16* __restrict__ Vt,
                                                 _Float16* __restrict__ Ob) {
    __shared__ __align__(16) _Float16 Ks[64 * 64];   // [k][d], XOR-swizzled 16B slots
    __shared__ __align__(16) _Float16 Vs[64 * 64];   // [d][k], XOR-swizzled 16B slots
    __shared__ __align__(16) _Float16 Ps[4][16 * 64];// per-wave P [q][k], swizzled

    const int qb = blockIdx.x, h = blockIdx.y;
    const int Q0 = qb * 64;
    const int kvh = h / 5;
    const int tid = threadIdx.x, l = tid & 63, w = tid >> 6;
    const int g = l >> 4, li = l & 15;
    const int qabs = Q0 + w * 16 + li;          // this lane's softmax row

    // Q fragments (A/B frag layout: row = lane&15, k-elems = (lane>>4)*8 + j)
    f16x8 qf[2];
#pragma unroll
    for (int dk = 0; dk < 2; ++dk)
        qf[dk] = *(const f16x8*)(Qh + ((size_t)h * SS + qabs) * 64 + dk * 32 + g * 8);

    float m_i = -1e30f, l_i = 0.0f;
    f32x4 o[4];
#pragma unroll
    for (int fn = 0; fn < 4; ++fn) o[fn] = (f32x4)0.0f;

    const int c_lo = (Q0 >= 1023) ? ((Q0 - 1023) >> 6) : 0;
    const int c_hi = qb;
    const int qw = Q0 + w * 16;

    for (int c = c_lo; c <= c_hi; ++c) {
        __syncthreads();
        // stage K tile [64 keys][64 d] and Vt tile [64 d][64 keys]; wave w stages rows w*16..+15
#pragma unroll
        for (int t = 0; t < 2; ++t) {
            int rloc = w * 16 + t * 8 + (l >> 3);
            int ss = (l & 7) ^ (l >> 3);    // pre-swizzled source slot (rloc&7 == l>>3)
            const _Float16* gK = Kh + ((size_t)kvh * SS + c * 64 + rloc) * 64 + ss * 8;
            const _Float16* gV = Vt + ((size_t)kvh * 64 + rloc) * SS + c * 64 + ss * 8;
            _Float16* lK = Ks + (w * 16 + t * 8) * 64;
            _Float16* lV = Vs + (w * 16 + t * 8) * 64;
            __builtin_amdgcn_global_load_lds((const __attribute__((address_space(1))) unsigned int*)gK,
                                             (__attribute__((address_space(3))) unsigned int*)lK, 16, 0, 0);
            __builtin_amdgcn_global_load_lds((const __attribute__((address_space(1))) unsigned int*)gV,
                                             (__attribute__((address_space(3))) unsigned int*)lV, 16, 0, 0);
        }
        __syncthreads();

        // wave-uniform chunk validity
        if (c * 64 <= qw + 15 && c * 64 + 63 >= qw - 1023) {
            // S^T = K @ Q^T : st[f] covers keys f*16..f*16+15 (rows), q cols
            f32x4 st[4];
#pragma unroll
            for (int f = 0; f < 4; ++f) st[f] = (f32x4)0.0f;
#pragma unroll
            for (int dk = 0; dk < 2; ++dk) {
#pragma unroll
                for (int f = 0; f < 4; ++f) {
                    int krow = f * 16 + li;
                    int ps = (dk * 4 + g) ^ (li & 7);
                    f16x8 kf = *(const f16x8*)(Ks + krow * 64 + ps * 8);
                    st[f] = __builtin_amdgcn_mfma_f32_16x16x32_f16(kf, qf[dk], st[f], 0, 0, 0);
                }
            }
            // mask (k = c*64 + f*16 + g*4 + reg ; q = qabs) and row-max
            float mx = -1e30f;
#pragma unroll
            for (int f = 0; f < 4; ++f)
#pragma unroll
                for (int reg = 0; reg < 4; ++reg) {
                    int kab = c * 64 + f * 16 + g * 4 + reg;
                    bool valid = (kab <= qabs) && (qabs - kab < 1024);
                    float s = valid ? st[f][reg] : -1e30f;
                    st[f][reg] = s;
                    mx = fmaxf(mx, s);
                }
            mx = fmaxf(mx, __shfl_xor(mx, 16));
            mx = fmaxf(mx, __shfl_xor(mx, 32));
            float m_new = fmaxf(fmaxf(m_i, mx), -1e20f);   // clamp: all-masked rows stay harmless

            float psum = 0.0f;
            char* Pw = (char*)&Ps[w][0] + li * 128;
#pragma unroll
            for (int f = 0; f < 4; ++f)
#pragma unroll
                for (int rp = 0; rp < 2; ++rp) {
                    float p0 = __expf(st[f][2 * rp]     - m_new);
                    float p1 = __expf(st[f][2 * rp + 1] - m_new);
                    psum += p0 + p1;
                    union { _Float16 hh[2]; unsigned u; } pk;
                    pk.hh[0] = (_Float16)p0; pk.hh[1] = (_Float16)p1;
                    int phys = (f * 2 + (g >> 1)) ^ (li & 7);
                    *(unsigned*)(Pw + phys * 16 + (g & 1) * 8 + rp * 4) = pk.u;
                }
            psum += __shfl_xor(psum, 16);
            psum += __shfl_xor(psum, 32);
            float corr = __expf(m_i - m_new);
            l_i = l_i * corr + psum;
            m_i = m_new;

            // rescale O (O rows q = g*4+reg -> fetch corr from lane g*4+reg)
            float c0 = __shfl(corr, g * 4 + 0);
            float c1 = __shfl(corr, g * 4 + 1);
            float c2 = __shfl(corr, g * 4 + 2);
            float c3 = __shfl(corr, g * 4 + 3);
#pragma unroll
            for (int fn = 0; fn < 4; ++fn) {
                o[fn][0] *= c0; o[fn][1] *= c1; o[fn][2] *= c2; o[fn][3] *= c3;
            }

            // PV: O[q][d] += P[q][k] V[k][d] = mfma(P_frag, Vt_frag)
#pragma unroll
            for (int kk = 0; kk < 2; ++kk) {
                int pp = (kk * 4 + g) ^ (li & 7);
                f16x8 pa = *(const f16x8*)(Pw + pp * 16);
#pragma unroll
                for (int fn = 0; fn < 4; ++fn) {
                    int drow = fn * 16 + li;
                    int vp = (kk * 4 + g) ^ (li & 7);
                    f16x8 vf = *(const f16x8*)(Vs + drow * 64 + vp * 8);
                    o[fn] = __builtin_amdgcn_mfma_f32_16x16x32_f16(pa, vf, o[fn], 0, 0, 0);
                }
            }
        }
    }

    // epilogue: O rows q = g*4+reg (abs Q0 + w*16 + q), cols d = fn*16 + li
#pragma unroll
    for (int reg = 0; reg < 4; ++reg) {
        float linv = 1.0f / __shfl(l_i, g * 4 + reg);
        int row = Q0 + w * 16 + g * 4 + reg;
#pragma unroll
        for (int fn = 0; fn < 4; ++fn)
            Ob[(size_t)row * HIDD + h * 64 + fn * 16 + li] = (_Float16)(o[fn][reg] * linv);
    }
}

// ---------------------------------------------------------------- launch
extern "C" void kernel_launch(void* const* d_in, const int* in_sizes, int n_in,
                              void* d_out, int out_size, void* d_ws, size_t ws_size,
                              hipStream_t stream) {
    const float* hs   = (const float*)d_in[0];
    const float* Wq   = (const float*)d_in[2];
    const float* Wk   = (const float*)d_in[3];
    const float* Wv   = (const float*)d_in[4];
    const float* Wo   = (const float*)d_in[5];
    const float* qlnw = (const float*)d_in[6];
    const float* klnw = (const float*)d_in[7];
    const float* qa   = (const float*)d_in[8];
    const float* ka   = (const float*)d_in[9];
    const float* va   = (const float*)d_in[10];
    const float* oa   = (const float*)d_in[11];

    char* ws = (char*)d_ws;
    _Float16* hsb   = (_Float16*)ws;                 ws += (size_t)SS * HIDD * 2;
    _Float16* wqkvb = (_Float16*)ws;                 ws += (size_t)NQKV * HIDD * 2;
    _Float16* wob   = (_Float16*)ws;                 ws += (size_t)HIDD * HIDD * 2;
    float*    qkv   = (float*)ws;                    ws += (size_t)SS * NQKV * 4;
    _Float16* Qhd   = (_Float16*)ws;                 ws += (size_t)HH * SS * DD * 2;
    _Float16* Khd   = (_Float16*)ws;                 ws += (size_t)KVHH * SS * DD * 2;
    _Float16* Vhd   = (_Float16*)ws;                 ws += (size_t)KVHH * SS * DD * 2;
    _Float16* Vtd   = (_Float16*)ws;                 ws += (size_t)KVHH * SS * DD * 2;
    _Float16* attnb = (_Float16*)ws;                 ws += (size_t)SS * HIDD * 2;

    cvt_f16<<<3840, 256, 0, stream>>>(hs, hsb, nullptr, SS * HIDD);
    cvt_f16<<<3600, 256, 0, stream>>>(Wq, wqkvb, qa, HIDD * HIDD);
    cvt_f16<<<720,  256, 0, stream>>>(Wk, wqkvb + (size_t)1920 * HIDD, ka, 384 * HIDD);
    cvt_f16<<<720,  256, 0, stream>>>(Wv, wqkvb + (size_t)2304 * HIDD, va, 384 * HIDD);
    cvt_f16<<<3600, 256, 0, stream>>>(Wo, wob, oa, HIDD * HIDD);

    gemm_bt_f16<<<dim3(NQKV / 128, SS / 128), 256, 0, stream>>>(hsb, wqkvb, qkv, SS, NQKV, HIDD);

    lnrope<<<(SS * 42) / 4, 256, 0, stream>>>(qkv, qlnw, klnw, Qhd, Khd, Vhd);

    transpose_v<<<dim3(SS / 64, KVHH), 256, 0, stream>>>(Vhd, Vtd);

    attn_mfma<<<dim3(SS / 64, HH), 256, 0, stream>>>(Qhd, Khd, Vtd, attnb);

    gemm_bt_f16<<<dim3(HIDD / 128, SS / 128), 256, 0, stream>>>(attnb, wob, (float*)d_out, SS, HIDD, HIDD);
}

// Round 3
// 165.059 us; speedup vs baseline: 6.2411x; 1.0473x over previous
//
#include <hip/hip_runtime.h>
#include <hip/hip_fp16.h>

#define SS 2048
#define HH 30
#define KVHH 6
#define DD 64
#define HIDD 1920
#define NQKV 2688   // 1920 (q) + 384 (k) + 384 (v)

typedef __attribute__((ext_vector_type(4))) float  f32x4;
typedef __attribute__((ext_vector_type(4))) float  float4v;
typedef __attribute__((ext_vector_type(8))) _Float16 f16x8;
typedef __attribute__((ext_vector_type(4))) _Float16 f16x4;

// ---------------------------------------------------------------- cvt f32->f16 (*alpha)
__global__ __launch_bounds__(256) void cvt_f16(const float* __restrict__ in,
                                               _Float16* __restrict__ out,
                                               const float* __restrict__ alpha, int n) {
    int i = (blockIdx.x * 256 + threadIdx.x) * 4;
    if (i >= n) return;
    float a = alpha ? alpha[0] : 1.0f;
    float4v v = *(const float4v*)(in + i);
    f16x4 o;
    o[0] = (_Float16)(v[0] * a);
    o[1] = (_Float16)(v[1] * a);
    o[2] = (_Float16)(v[2] * a);
    o[3] = (_Float16)(v[3] * a);
    *(f16x4*)(out + i) = o;
}

// ---------------------------------------------------------------- GEMM: C[M][N] = A[M][K] * B[N][K]^T
__global__ __launch_bounds__(256) void gemm_bt_f16(const _Float16* __restrict__ A,
                                                   const _Float16* __restrict__ B,
                                                   float* __restrict__ C,
                                                   int M, int N, int K) {
    __shared__ __align__(16) _Float16 As[128 * 64];
    __shared__ __align__(16) _Float16 Bs[128 * 64];
    const int tid = threadIdx.x;
    const int l   = tid & 63;
    const int w   = tid >> 6;
    const int wm  = (w >> 1) * 64;
    const int wn  = (w & 1) * 64;
    const int m0  = blockIdx.y * 128;
    const int n0  = blockIdx.x * 128;

    f32x4 acc[4][4];
#pragma unroll
    for (int a = 0; a < 4; ++a)
#pragma unroll
        for (int b = 0; b < 4; ++b) acc[a][b] = (f32x4)0.0f;

    for (int kt = 0; kt < K; kt += 64) {
#pragma unroll
        for (int it = 0; it < 4; ++it) {
            int g = it * 256 + tid;
            int row = g >> 3;
            int s   = (g & 7) ^ (row & 7);
            const _Float16* gA = A + (size_t)(m0 + row) * K + kt + s * 8;
            const _Float16* gB = B + (size_t)(n0 + row) * K + kt + s * 8;
            _Float16* lA = As + (size_t)(it * 256 + w * 64) * 8;
            _Float16* lB = Bs + (size_t)(it * 256 + w * 64) * 8;
            __builtin_amdgcn_global_load_lds((const __attribute__((address_space(1))) unsigned int*)gA,
                                             (__attribute__((address_space(3))) unsigned int*)lA, 16, 0, 0);
            __builtin_amdgcn_global_load_lds((const __attribute__((address_space(1))) unsigned int*)gB,
                                             (__attribute__((address_space(3))) unsigned int*)lB, 16, 0, 0);
        }
        __syncthreads();

#pragma unroll
        for (int kk = 0; kk < 2; ++kk) {
            f16x8 af[4], bf[4];
#pragma unroll
            for (int fm = 0; fm < 4; ++fm) {
                int row = wm + fm * 16 + (l & 15);
                int s   = (kk * 4 + (l >> 4)) ^ (row & 7);
                af[fm] = *(const f16x8*)(As + row * 64 + s * 8);
            }
#pragma unroll
            for (int fn = 0; fn < 4; ++fn) {
                int row = wn + fn * 16 + (l & 15);
                int s   = (kk * 4 + (l >> 4)) ^ (row & 7);
                bf[fn] = *(const f16x8*)(Bs + row * 64 + s * 8);
            }
#pragma unroll
            for (int fm = 0; fm < 4; ++fm)
#pragma unroll
                for (int fn = 0; fn < 4; ++fn)
                    acc[fm][fn] = __builtin_amdgcn_mfma_f32_16x16x32_f16(af[fm], bf[fn], acc[fm][fn], 0, 0, 0);
        }
        __syncthreads();
    }

#pragma unroll
    for (int fm = 0; fm < 4; ++fm)
#pragma unroll
        for (int fn = 0; fn < 4; ++fn)
#pragma unroll
            for (int j = 0; j < 4; ++j) {
                int r = m0 + wm + fm * 16 + (l >> 4) * 4 + j;
                int c = n0 + wn + fn * 16 + (l & 15);
                C[(size_t)r * N + c] = acc[fm][fn][j];
            }
}

// ---------------------------------------------------------------- per-head LN + RoPE + reformat
__global__ __launch_bounds__(256) void lnrope(const float* __restrict__ qkv,
                                              const float* __restrict__ qlnw,
                                              const float* __restrict__ klnw,
                                              _Float16* __restrict__ Qh,
                                              _Float16* __restrict__ Kh,
                                              _Float16* __restrict__ Vh) {
    int task = blockIdx.x * 4 + (threadIdx.x >> 6);
    int lane = threadIdx.x & 63;
    int s = task / 42;
    int u = task % 42;
    if (s >= SS) return;

    if (u < 36) {
        int head  = (u < 30) ? u : (u - 30);
        int col   = (u < 30) ? (u * 64 + lane) : (1920 + head * 64 + lane);
        const float* lw = (u < 30) ? qlnw : klnw;
        float x = qkv[(size_t)s * NQKV + col];

        float mu = x;
#pragma unroll
        for (int off = 32; off; off >>= 1) mu += __shfl_xor(mu, off);
        mu *= (1.0f / 64.0f);
        float d = x - mu;
        float var = d * d;
#pragma unroll
        for (int off = 32; off; off >>= 1) var += __shfl_xor(var, off);
        var *= (1.0f / 64.0f);
        float xn = d * rsqrtf(var + 1e-5f) * lw[head * 64 + lane];

        float f = exp2f(-13.287712379549449f * (float)(lane & 31) * (1.0f / 32.0f));
        float ang = (float)s * f;
        float sn, cs;
        sincosf(ang, &sn, &cs);
        float prt = __shfl_xor(xn, 32);
        float rot = (lane < 32) ? -prt : prt;
        float r = xn * cs + rot * sn;

        if (u < 30) Qh[((size_t)head * SS + s) * 64 + lane] = (_Float16)(r * 0.125f);
        else        Kh[((size_t)head * SS + s) * 64 + lane] = (_Float16)r;
    } else {
        int head = u - 36;
        float x = qkv[(size_t)s * NQKV + 2304 + head * 64 + lane];
        Vh[((size_t)head * SS + s) * 64 + lane] = (_Float16)x;
    }
}

// ---------------------------------------------------------------- V transpose: Vh[h][s][d] -> Vt[h][d][s]
__global__ __launch_bounds__(256) void transpose_v(const _Float16* __restrict__ Vh,
                                                   _Float16* __restrict__ Vt) {
    __shared__ _Float16 T[64][68];
    const int s0 = blockIdx.x * 64;
    const int h  = blockIdx.y;
    const int tid = threadIdx.x;
#pragma unroll
    for (int pass = 0; pass < 2; ++pass) {
        int idx = pass * 256 + tid;
        int r = idx >> 3, d0 = (idx & 7) * 8;
        f16x8 v = *(const f16x8*)(Vh + ((size_t)(h * SS + s0 + r)) * 64 + d0);
#pragma unroll
        for (int j = 0; j < 8; ++j) T[r][d0 + j] = v[j];
    }
    __syncthreads();
#pragma unroll
    for (int pass = 0; pass < 2; ++pass) {
        int idx = pass * 256 + tid;
        int d = idx >> 3, c0 = (idx & 7) * 8;
        f16x8 o;
#pragma unroll
        for (int j = 0; j < 8; ++j) o[j] = T[c0 + j][d];
        *(f16x8*)(Vt + ((size_t)(h * 64 + d)) * SS + s0 + c0) = o;
    }
}

// ---------------------------------------------------------------- MFMA sliding-window attention
// block = (qblock of 64 rows, head). 4 waves, wave w owns q rows w*16..w*16+15.
// Swapped QK^T; double-buffered K/V staging (1 barrier/chunk); interior-chunk
// mask skip; defer-max (THR=6, m floor -1e20); setprio around MFMA.
#define ATTN_STAGE(buf, c)                                                                             \
    do {                                                                                               \
        _Pragma("unroll")                                                                              \
        for (int t = 0; t < 2; ++t) {                                                                  \
            int rloc = w * 16 + t * 8 + (l >> 3);                                                      \
            int ss = (l & 7) ^ (l >> 3);                                                               \
            const _Float16* gK = Kh + ((size_t)kvh * SS + (c) * 64 + rloc) * 64 + ss * 8;              \
            const _Float16* gV = Vt + ((size_t)kvh * 64 + rloc) * SS + (c) * 64 + ss * 8;              \
            _Float16* lK = Ks[buf] + (w * 16 + t * 8) * 64;                                            \
            _Float16* lV = Vs[buf] + (w * 16 + t * 8) * 64;                                            \
            __builtin_amdgcn_global_load_lds((const __attribute__((address_space(1))) unsigned int*)gK,\
                                             (__attribute__((address_space(3))) unsigned int*)lK, 16, 0, 0); \
            __builtin_amdgcn_global_load_lds((const __attribute__((address_space(1))) unsigned int*)gV,\
                                             (__attribute__((address_space(3))) unsigned int*)lV, 16, 0, 0); \
        }                                                                                              \
    } while (0)

__global__ __launch_bounds__(256) void attn_mfma(const _Float16* __restrict__ Qh,
                                                 const _Float16* __restrict__ Kh,
                                                 const _Float16* __restrict__ Vt,
                                                 _Float16* __restrict__ Ob) {
    __shared__ __align__(16) _Float16 Ks[2][64 * 64];
    __shared__ __align__(16) _Float16 Vs[2][64 * 64];
    __shared__ __align__(16) _Float16 Ps[4][16 * 64];

    const int qb = 31 - blockIdx.x;          // long blocks dispatch first
    const int h = blockIdx.y;
    const int Q0 = qb * 64;
    const int kvh = h / 5;
    const int tid = threadIdx.x, l = tid & 63, w = tid >> 6;
    const int g = l >> 4, li = l & 15;
    const int qabs = Q0 + w * 16 + li;

    f16x8 qf[2];
#pragma unroll
    for (int dk = 0; dk < 2; ++dk)
        qf[dk] = *(const f16x8*)(Qh + ((size_t)h * SS + qabs) * 64 + dk * 32 + g * 8);

    float m_i = -1e20f, l_i = 0.0f;          // m floor -1e20: defer-safe for masked rows
    f32x4 o[4];
#pragma unroll
    for (int fn = 0; fn < 4; ++fn) o[fn] = (f32x4)0.0f;

    const int c_lo = (Q0 >= 1023) ? ((Q0 - 1023) >> 6) : 0;
    const int c_hi = qb;
    const int qw = Q0 + w * 16;

    ATTN_STAGE(0, c_lo);
    __syncthreads();

    for (int c = c_lo; c <= c_hi; ++c) {
        const int nb = (c - c_lo) & 1;
        if (c < c_hi) ATTN_STAGE(nb ^ 1, c + 1);   // overlap next-chunk loads with compute

        if (c * 64 <= qw + 15 && c * 64 + 63 >= qw - 1023) {
            const _Float16* Kb = Ks[nb];
            const _Float16* Vb = Vs[nb];
            const bool full = (c * 64 + 63 <= qw) && (c * 64 >= qw + 15 - 1023);

            f32x4 st[4];
#pragma unroll
            for (int f = 0; f < 4; ++f) st[f] = (f32x4)0.0f;
            __builtin_amdgcn_s_setprio(1);
#pragma unroll
            for (int dk = 0; dk < 2; ++dk) {
#pragma unroll
                for (int f = 0; f < 4; ++f) {
                    int ps = (dk * 4 + g) ^ (li & 7);
                    f16x8 kf = *(const f16x8*)(Kb + (f * 16 + li) * 64 + ps * 8);
                    st[f] = __builtin_amdgcn_mfma_f32_16x16x32_f16(kf, qf[dk], st[f], 0, 0, 0);
                }
            }
            __builtin_amdgcn_s_setprio(0);

            if (!full) {
#pragma unroll
                for (int f = 0; f < 4; ++f)
#pragma unroll
                    for (int reg = 0; reg < 4; ++reg) {
                        int kab = c * 64 + f * 16 + g * 4 + reg;
                        bool valid = (kab <= qabs) && (qabs - kab < 1024);
                        st[f][reg] = valid ? st[f][reg] : -1e30f;
                    }
            }
            float mx = -1e30f;
#pragma unroll
            for (int f = 0; f < 4; ++f)
#pragma unroll
                for (int reg = 0; reg < 4; ++reg) mx = fmaxf(mx, st[f][reg]);
            mx = fmaxf(mx, __shfl_xor(mx, 16));
            mx = fmaxf(mx, __shfl_xor(mx, 32));

            if (__any(mx > m_i + 6.0f)) {          // rescale path (rare on interior chunks)
                float m_new = fmaxf(m_i, mx);      // m_i >= -1e20 keeps the floor
                float corr = __expf(m_i - m_new);
                m_i = m_new;
                l_i *= corr;
                float c0 = __shfl(corr, g * 4 + 0);
                float c1 = __shfl(corr, g * 4 + 1);
                float c2 = __shfl(corr, g * 4 + 2);
                float c3 = __shfl(corr, g * 4 + 3);
#pragma unroll
                for (int fn = 0; fn < 4; ++fn) {
                    o[fn][0] *= c0; o[fn][1] *= c1; o[fn][2] *= c2; o[fn][3] *= c3;
                }
            }

            float psum = 0.0f;
            char* Pw = (char*)&Ps[w][0] + li * 128;
#pragma unroll
            for (int f = 0; f < 4; ++f)
#pragma unroll
                for (int rp = 0; rp < 2; ++rp) {
                    float p0 = __expf(st[f][2 * rp]     - m_i);
                    float p1 = __expf(st[f][2 * rp + 1] - m_i);
                    psum += p0 + p1;
                    union { _Float16 hh[2]; unsigned u; } pk;
                    pk.hh[0] = (_Float16)p0; pk.hh[1] = (_Float16)p1;
                    int phys = (f * 2 + (g >> 1)) ^ (li & 7);
                    *(unsigned*)(Pw + phys * 16 + (g & 1) * 8 + rp * 4) = pk.u;
                }
            psum += __shfl_xor(psum, 16);
            psum += __shfl_xor(psum, 32);
            l_i += psum;

            __builtin_amdgcn_s_setprio(1);
#pragma unroll
            for (int kk = 0; kk < 2; ++kk) {
                int pp = (kk * 4 + g) ^ (li & 7);
                f16x8 pa = *(const f16x8*)(Pw + pp * 16);
#pragma unroll
                for (int fn = 0; fn < 4; ++fn) {
                    int drow = fn * 16 + li;
                    int vp = (kk * 4 + g) ^ (li & 7);
                    f16x8 vf = *(const f16x8*)(Vb + drow * 64 + vp * 8);
                    o[fn] = __builtin_amdgcn_mfma_f32_16x16x32_f16(pa, vf, o[fn], 0, 0, 0);
                }
            }
            __builtin_amdgcn_s_setprio(0);
        }
        __syncthreads();   // protects re-staged buffer + drains this wave's prefetch
    }

#pragma unroll
    for (int reg = 0; reg < 4; ++reg) {
        float linv = 1.0f / __shfl(l_i, g * 4 + reg);
        int row = Q0 + w * 16 + g * 4 + reg;
#pragma unroll
        for (int fn = 0; fn < 4; ++fn)
            Ob[(size_t)row * HIDD + h * 64 + fn * 16 + li] = (_Float16)(o[fn][reg] * linv);
    }
}

// ---------------------------------------------------------------- launch
extern "C" void kernel_launch(void* const* d_in, const int* in_sizes, int n_in,
                              void* d_out, int out_size, void* d_ws, size_t ws_size,
                              hipStream_t stream) {
    const float* hs   = (const float*)d_in[0];
    const float* Wq   = (const float*)d_in[2];
    const float* Wk   = (const float*)d_in[3];
    const float* Wv   = (const float*)d_in[4];
    const float* Wo   = (const float*)d_in[5];
    const float* qlnw = (const float*)d_in[6];
    const float* klnw = (const float*)d_in[7];
    const float* qa   = (const float*)d_in[8];
    const float* ka   = (const float*)d_in[9];
    const float* va   = (const float*)d_in[10];
    const float* oa   = (const float*)d_in[11];

    char* ws = (char*)d_ws;
    _Float16* hsb   = (_Float16*)ws;                 ws += (size_t)SS * HIDD * 2;
    _Float16* wqkvb = (_Float16*)ws;                 ws += (size_t)NQKV * HIDD * 2;
    _Float16* wob   = (_Float16*)ws;                 ws += (size_t)HIDD * HIDD * 2;
    float*    qkv   = (float*)ws;                    ws += (size_t)SS * NQKV * 4;
    _Float16* Qhd   = (_Float16*)ws;                 ws += (size_t)HH * SS * DD * 2;
    _Float16* Khd   = (_Float16*)ws;                 ws += (size_t)KVHH * SS * DD * 2;
    _Float16* Vhd   = (_Float16*)ws;                 ws += (size_t)KVHH * SS * DD * 2;
    _Float16* Vtd   = (_Float16*)ws;                 ws += (size_t)KVHH * SS * DD * 2;
    _Float16* attnb = (_Float16*)ws;                 ws += (size_t)SS * HIDD * 2;

    cvt_f16<<<3840, 256, 0, stream>>>(hs, hsb, nullptr, SS * HIDD);
    cvt_f16<<<3600, 256, 0, stream>>>(Wq, wqkvb, qa, HIDD * HIDD);
    cvt_f16<<<720,  256, 0, stream>>>(Wk, wqkvb + (size_t)1920 * HIDD, ka, 384 * HIDD);
    cvt_f16<<<720,  256, 0, stream>>>(Wv, wqkvb + (size_t)2304 * HIDD, va, 384 * HIDD);
    cvt_f16<<<3600, 256, 0, stream>>>(Wo, wob, oa, HIDD * HIDD);

    gemm_bt_f16<<<dim3(NQKV / 128, SS / 128), 256, 0, stream>>>(hsb, wqkvb, qkv, SS, NQKV, HIDD);

    lnrope<<<(SS * 42) / 4, 256, 0, stream>>>(qkv, qlnw, klnw, Qhd, Khd, Vhd);

    transpose_v<<<dim3(SS / 64, KVHH), 256, 0, stream>>>(Vhd, Vtd);

    attn_mfma<<<dim3(SS / 64, HH), 256, 0, stream>>>(Qhd, Khd, Vtd, attnb);

    gemm_bt_f16<<<dim3(HIDD / 128, SS / 128), 256, 0, stream>>>(attnb, wob, (float*)d_out, SS, HIDD, HIDD);
}

// Round 4
// 150.549 us; speedup vs baseline: 6.8426x; 1.0964x over previous
//
#include <hip/hip_runtime.h>
#include <hip/hip_fp16.h>

#define SS 2048
#define HH 30
#define KVHH 6
#define DD 64
#define HIDD 1920
#define NQKV 2688   // 1920 (q) + 384 (k) + 384 (v)

typedef __attribute__((ext_vector_type(4))) float  f32x4;
typedef __attribute__((ext_vector_type(4))) float  float4v;
typedef __attribute__((ext_vector_type(8))) _Float16 f16x8;
typedef __attribute__((ext_vector_type(4))) _Float16 f16x4;

// ---------------------------------------------------------------- fused f32->f16 cvt (*alpha), 5 regions, 1024 elems/block
__global__ __launch_bounds__(256) void cvt_all(const float* __restrict__ hs,
                                               const float* __restrict__ Wq,
                                               const float* __restrict__ Wk,
                                               const float* __restrict__ Wv,
                                               const float* __restrict__ Wo,
                                               _Float16* __restrict__ hsb,
                                               _Float16* __restrict__ wqkvb,
                                               _Float16* __restrict__ wob,
                                               const float* __restrict__ qa,
                                               const float* __restrict__ ka,
                                               const float* __restrict__ va,
                                               const float* __restrict__ oa) {
    int b = blockIdx.x;
    const float* in; _Float16* out; float a; int base;
    if (b < 3840)      { in = hs; out = hsb;              a = 1.0f;  base = b; }
    else if (b < 7440) { in = Wq; out = wqkvb;            a = qa[0]; base = b - 3840; }
    else if (b < 8160) { in = Wk; out = wqkvb + 3686400;  a = ka[0]; base = b - 7440; }
    else if (b < 8880) { in = Wv; out = wqkvb + 4423680;  a = va[0]; base = b - 8160; }
    else               { in = Wo; out = wob;              a = oa[0]; base = b - 8880; }
    int i = base * 1024 + threadIdx.x * 4;
    float4v v = *(const float4v*)(in + i);
    f16x4 o;
    o[0] = (_Float16)(v[0] * a);
    o[1] = (_Float16)(v[1] * a);
    o[2] = (_Float16)(v[2] * a);
    o[3] = (_Float16)(v[3] * a);
    *(f16x4*)(out + i) = o;
}

// ---------------------------------------------------------------- split-K GEMM: Cpart[z][M][N] = A[M][kchunk] * B[N][kchunk]^T
// grid (Ntiles, Mtiles, SPLITK); flattened-bid bijective XCD swizzle (nwg % 8 == 0).
__global__ __launch_bounds__(256) void gemm_bt_f16(const _Float16* __restrict__ A,
                                                   const _Float16* __restrict__ B,
                                                   float* __restrict__ C,
                                                   int M, int N, int K) {
    __shared__ __align__(16) _Float16 As[128 * 64];
    __shared__ __align__(16) _Float16 Bs[128 * 64];
    const int tid = threadIdx.x;
    const int l   = tid & 63;
    const int w   = tid >> 6;
    const int wm  = (w >> 1) * 64;
    const int wn  = (w & 1) * 64;

    // XCD swizzle: consecutive logical tiles (same A panel) -> same XCD L2
    const int gx  = gridDim.x;
    const int nxy = gx * gridDim.y;
    const int nwg = nxy * gridDim.z;
    int bid = (blockIdx.z * gridDim.y + blockIdx.y) * gx + blockIdx.x;
    int lid = (bid & 7) * (nwg >> 3) + (bid >> 3);
    int z   = lid / nxy;  int rem = lid - z * nxy;
    int by  = rem / gx;   int bx  = rem - by * gx;

    const int m0 = by * 128;
    const int n0 = bx * 128;
    const int kchunk = K / gridDim.z;
    const int kt0 = z * kchunk;
    float* Cp = C + (size_t)z * M * N;

    f32x4 acc[4][4];
#pragma unroll
    for (int a = 0; a < 4; ++a)
#pragma unroll
        for (int b = 0; b < 4; ++b) acc[a][b] = (f32x4)0.0f;

    for (int kt = kt0; kt < kt0 + kchunk; kt += 64) {
#pragma unroll
        for (int it = 0; it < 4; ++it) {
            int g = it * 256 + tid;
            int row = g >> 3;
            int s   = (g & 7) ^ (row & 7);
            const _Float16* gA = A + (size_t)(m0 + row) * K + kt + s * 8;
            const _Float16* gB = B + (size_t)(n0 + row) * K + kt + s * 8;
            _Float16* lA = As + (size_t)(it * 256 + w * 64) * 8;
            _Float16* lB = Bs + (size_t)(it * 256 + w * 64) * 8;
            __builtin_amdgcn_global_load_lds((const __attribute__((address_space(1))) unsigned int*)gA,
                                             (__attribute__((address_space(3))) unsigned int*)lA, 16, 0, 0);
            __builtin_amdgcn_global_load_lds((const __attribute__((address_space(1))) unsigned int*)gB,
                                             (__attribute__((address_space(3))) unsigned int*)lB, 16, 0, 0);
        }
        __syncthreads();

#pragma unroll
        for (int kk = 0; kk < 2; ++kk) {
            f16x8 af[4], bf[4];
#pragma unroll
            for (int fm = 0; fm < 4; ++fm) {
                int row = wm + fm * 16 + (l & 15);
                int s   = (kk * 4 + (l >> 4)) ^ (row & 7);
                af[fm] = *(const f16x8*)(As + row * 64 + s * 8);
            }
#pragma unroll
            for (int fn = 0; fn < 4; ++fn) {
                int row = wn + fn * 16 + (l & 15);
                int s   = (kk * 4 + (l >> 4)) ^ (row & 7);
                bf[fn] = *(const f16x8*)(Bs + row * 64 + s * 8);
            }
#pragma unroll
            for (int fm = 0; fm < 4; ++fm)
#pragma unroll
                for (int fn = 0; fn < 4; ++fn)
                    acc[fm][fn] = __builtin_amdgcn_mfma_f32_16x16x32_f16(af[fm], bf[fn], acc[fm][fn], 0, 0, 0);
        }
        __syncthreads();
    }

#pragma unroll
    for (int fm = 0; fm < 4; ++fm)
#pragma unroll
        for (int fn = 0; fn < 4; ++fn)
#pragma unroll
            for (int j = 0; j < 4; ++j) {
                int r = m0 + wm + fm * 16 + (l >> 4) * 4 + j;
                int c = n0 + wn + fn * 16 + (l & 15);
                Cp[(size_t)r * N + c] = acc[fm][fn][j];
            }
}

// ---------------------------------------------------------------- add two fp32 partials -> d_out
__global__ __launch_bounds__(256) void add2_f32(const float* __restrict__ p0,
                                                const float* __restrict__ p1,
                                                float* __restrict__ out) {
    int i = (blockIdx.x * 256 + threadIdx.x) * 4;
    float4v a = *(const float4v*)(p0 + i);
    float4v b = *(const float4v*)(p1 + i);
    float4v r;
    r[0] = a[0] + b[0]; r[1] = a[1] + b[1]; r[2] = a[2] + b[2]; r[3] = a[3] + b[3];
    *(float4v*)(out + i) = r;
}

// ---------------------------------------------------------------- per-head LN + RoPE + reformat (sums 2 split-K partials)
__global__ __launch_bounds__(256) void lnrope2(const float* __restrict__ q0,
                                               const float* __restrict__ q1,
                                               const float* __restrict__ qlnw,
                                               const float* __restrict__ klnw,
                                               _Float16* __restrict__ Qh,
                                               _Float16* __restrict__ Kh,
                                               _Float16* __restrict__ Vh) {
    int task = blockIdx.x * 4 + (threadIdx.x >> 6);
    int lane = threadIdx.x & 63;
    int s = task / 42;
    int u = task % 42;
    if (s >= SS) return;

    if (u < 36) {
        int head  = (u < 30) ? u : (u - 30);
        int col   = (u < 30) ? (u * 64 + lane) : (1920 + head * 64 + lane);
        const float* lw = (u < 30) ? qlnw : klnw;
        size_t idx = (size_t)s * NQKV + col;
        float x = q0[idx] + q1[idx];

        float mu = x;
#pragma unroll
        for (int off = 32; off; off >>= 1) mu += __shfl_xor(mu, off);
        mu *= (1.0f / 64.0f);
        float d = x - mu;
        float var = d * d;
#pragma unroll
        for (int off = 32; off; off >>= 1) var += __shfl_xor(var, off);
        var *= (1.0f / 64.0f);
        float xn = d * rsqrtf(var + 1e-5f) * lw[head * 64 + lane];

        float f = exp2f(-13.287712379549449f * (float)(lane & 31) * (1.0f / 32.0f));
        float ang = (float)s * f;
        float sn, cs;
        sincosf(ang, &sn, &cs);
        float prt = __shfl_xor(xn, 32);
        float rot = (lane < 32) ? -prt : prt;
        float r = xn * cs + rot * sn;

        if (u < 30) Qh[((size_t)head * SS + s) * 64 + lane] = (_Float16)(r * 0.125f);
        else        Kh[((size_t)head * SS + s) * 64 + lane] = (_Float16)r;
    } else {
        int head = u - 36;
        size_t idx = (size_t)s * NQKV + 2304 + head * 64 + lane;
        float x = q0[idx] + q1[idx];
        Vh[((size_t)head * SS + s) * 64 + lane] = (_Float16)x;
    }
}

// ---------------------------------------------------------------- V transpose: Vh[h][s][d] -> Vt[h][d][s]
__global__ __launch_bounds__(256) void transpose_v(const _Float16* __restrict__ Vh,
                                                   _Float16* __restrict__ Vt) {
    __shared__ _Float16 T[64][68];
    const int s0 = blockIdx.x * 64;
    const int h  = blockIdx.y;
    const int tid = threadIdx.x;
#pragma unroll
    for (int pass = 0; pass < 2; ++pass) {
        int idx = pass * 256 + tid;
        int r = idx >> 3, d0 = (idx & 7) * 8;
        f16x8 v = *(const f16x8*)(Vh + ((size_t)(h * SS + s0 + r)) * 64 + d0);
#pragma unroll
        for (int j = 0; j < 8; ++j) T[r][d0 + j] = v[j];
    }
    __syncthreads();
#pragma unroll
    for (int pass = 0; pass < 2; ++pass) {
        int idx = pass * 256 + tid;
        int d = idx >> 3, c0 = (idx & 7) * 8;
        f16x8 o;
#pragma unroll
        for (int j = 0; j < 8; ++j) o[j] = T[c0 + j][d];
        *(f16x8*)(Vt + ((size_t)(h * 64 + d)) * SS + s0 + c0) = o;
    }
}

// ---------------------------------------------------------------- MFMA sliding-window attention
#define ATTN_STAGE(buf, c)                                                                             \
    do {                                                                                               \
        _Pragma("unroll")                                                                              \
        for (int t = 0; t < 2; ++t) {                                                                  \
            int rloc = w * 16 + t * 8 + (l >> 3);                                                      \
            int ss = (l & 7) ^ (l >> 3);                                                               \
            const _Float16* gK = Kh + ((size_t)kvh * SS + (c) * 64 + rloc) * 64 + ss * 8;              \
            const _Float16* gV = Vt + ((size_t)kvh * 64 + rloc) * SS + (c) * 64 + ss * 8;              \
            _Float16* lK = Ks[buf] + (w * 16 + t * 8) * 64;                                            \
            _Float16* lV = Vs[buf] + (w * 16 + t * 8) * 64;                                            \
            __builtin_amdgcn_global_load_lds((const __attribute__((address_space(1))) unsigned int*)gK,\
                                             (__attribute__((address_space(3))) unsigned int*)lK, 16, 0, 0); \
            __builtin_amdgcn_global_load_lds((const __attribute__((address_space(1))) unsigned int*)gV,\
                                             (__attribute__((address_space(3))) unsigned int*)lV, 16, 0, 0); \
        }                                                                                              \
    } while (0)

__global__ __launch_bounds__(256) void attn_mfma(const _Float16* __restrict__ Qh,
                                                 const _Float16* __restrict__ Kh,
                                                 const _Float16* __restrict__ Vt,
                                                 _Float16* __restrict__ Ob) {
    __shared__ __align__(16) _Float16 Ks[2][64 * 64];
    __shared__ __align__(16) _Float16 Vs[2][64 * 64];
    __shared__ __align__(16) _Float16 Ps[4][16 * 64];

    const int qb = 31 - blockIdx.x;
    const int h = blockIdx.y;
    const int Q0 = qb * 64;
    const int kvh = h / 5;
    const int tid = threadIdx.x, l = tid & 63, w = tid >> 6;
    const int g = l >> 4, li = l & 15;
    const int qabs = Q0 + w * 16 + li;

    f16x8 qf[2];
#pragma unroll
    for (int dk = 0; dk < 2; ++dk)
        qf[dk] = *(const f16x8*)(Qh + ((size_t)h * SS + qabs) * 64 + dk * 32 + g * 8);

    float m_i = -1e20f, l_i = 0.0f;
    f32x4 o[4];
#pragma unroll
    for (int fn = 0; fn < 4; ++fn) o[fn] = (f32x4)0.0f;

    const int c_lo = (Q0 >= 1023) ? ((Q0 - 1023) >> 6) : 0;
    const int c_hi = qb;
    const int qw = Q0 + w * 16;

    ATTN_STAGE(0, c_lo);
    __syncthreads();

    for (int c = c_lo; c <= c_hi; ++c) {
        const int nb = (c - c_lo) & 1;
        if (c < c_hi) ATTN_STAGE(nb ^ 1, c + 1);

        if (c * 64 <= qw + 15 && c * 64 + 63 >= qw - 1023) {
            const _Float16* Kb = Ks[nb];
            const _Float16* Vb = Vs[nb];
            const bool full = (c * 64 + 63 <= qw) && (c * 64 >= qw + 15 - 1023);

            f32x4 st[4];
#pragma unroll
            for (int f = 0; f < 4; ++f) st[f] = (f32x4)0.0f;
            __builtin_amdgcn_s_setprio(1);
#pragma unroll
            for (int dk = 0; dk < 2; ++dk) {
#pragma unroll
                for (int f = 0; f < 4; ++f) {
                    int ps = (dk * 4 + g) ^ (li & 7);
                    f16x8 kf = *(const f16x8*)(Kb + (f * 16 + li) * 64 + ps * 8);
                    st[f] = __builtin_amdgcn_mfma_f32_16x16x32_f16(kf, qf[dk], st[f], 0, 0, 0);
                }
            }
            __builtin_amdgcn_s_setprio(0);

            if (!full) {
#pragma unroll
                for (int f = 0; f < 4; ++f)
#pragma unroll
                    for (int reg = 0; reg < 4; ++reg) {
                        int kab = c * 64 + f * 16 + g * 4 + reg;
                        bool valid = (kab <= qabs) && (qabs - kab < 1024);
                        st[f][reg] = valid ? st[f][reg] : -1e30f;
                    }
            }
            float mx = -1e30f;
#pragma unroll
            for (int f = 0; f < 4; ++f)
#pragma unroll
                for (int reg = 0; reg < 4; ++reg) mx = fmaxf(mx, st[f][reg]);
            mx = fmaxf(mx, __shfl_xor(mx, 16));
            mx = fmaxf(mx, __shfl_xor(mx, 32));

            if (__any(mx > m_i + 6.0f)) {
                float m_new = fmaxf(m_i, mx);
                float corr = __expf(m_i - m_new);
                m_i = m_new;
                l_i *= corr;
                float c0 = __shfl(corr, g * 4 + 0);
                float c1 = __shfl(corr, g * 4 + 1);
                float c2 = __shfl(corr, g * 4 + 2);
                float c3 = __shfl(corr, g * 4 + 3);
#pragma unroll
                for (int fn = 0; fn < 4; ++fn) {
                    o[fn][0] *= c0; o[fn][1] *= c1; o[fn][2] *= c2; o[fn][3] *= c3;
                }
            }

            float psum = 0.0f;
            char* Pw = (char*)&Ps[w][0] + li * 128;
#pragma unroll
            for (int f = 0; f < 4; ++f)
#pragma unroll
                for (int rp = 0; rp < 2; ++rp) {
                    float p0 = __expf(st[f][2 * rp]     - m_i);
                    float p1 = __expf(st[f][2 * rp + 1] - m_i);
                    psum += p0 + p1;
                    union { _Float16 hh[2]; unsigned u; } pk;
                    pk.hh[0] = (_Float16)p0; pk.hh[1] = (_Float16)p1;
                    int phys = (f * 2 + (g >> 1)) ^ (li & 7);
                    *(unsigned*)(Pw + phys * 16 + (g & 1) * 8 + rp * 4) = pk.u;
                }
            psum += __shfl_xor(psum, 16);
            psum += __shfl_xor(psum, 32);
            l_i += psum;

            __builtin_amdgcn_s_setprio(1);
#pragma unroll
            for (int kk = 0; kk < 2; ++kk) {
                int pp = (kk * 4 + g) ^ (li & 7);
                f16x8 pa = *(const f16x8*)(Pw + pp * 16);
#pragma unroll
                for (int fn = 0; fn < 4; ++fn) {
                    int drow = fn * 16 + li;
                    int vp = (kk * 4 + g) ^ (li & 7);
                    f16x8 vf = *(const f16x8*)(Vb + drow * 64 + vp * 8);
                    o[fn] = __builtin_amdgcn_mfma_f32_16x16x32_f16(pa, vf, o[fn], 0, 0, 0);
                }
            }
            __builtin_amdgcn_s_setprio(0);
        }
        __syncthreads();
    }

#pragma unroll
    for (int reg = 0; reg < 4; ++reg) {
        float linv = 1.0f / __shfl(l_i, g * 4 + reg);
        int row = Q0 + w * 16 + g * 4 + reg;
#pragma unroll
        for (int fn = 0; fn < 4; ++fn)
            Ob[(size_t)row * HIDD + h * 64 + fn * 16 + li] = (_Float16)(o[fn][reg] * linv);
    }
}

// ---------------------------------------------------------------- launch
extern "C" void kernel_launch(void* const* d_in, const int* in_sizes, int n_in,
                              void* d_out, int out_size, void* d_ws, size_t ws_size,
                              hipStream_t stream) {
    const float* hs   = (const float*)d_in[0];
    const float* Wq   = (const float*)d_in[2];
    const float* Wk   = (const float*)d_in[3];
    const float* Wv   = (const float*)d_in[4];
    const float* Wo   = (const float*)d_in[5];
    const float* qlnw = (const float*)d_in[6];
    const float* klnw = (const float*)d_in[7];
    const float* qa   = (const float*)d_in[8];
    const float* ka   = (const float*)d_in[9];
    const float* va   = (const float*)d_in[10];
    const float* oa   = (const float*)d_in[11];

    char* ws = (char*)d_ws;
    _Float16* hsb   = (_Float16*)ws;                 ws += (size_t)SS * HIDD * 2;
    _Float16* wqkvb = (_Float16*)ws;                 ws += (size_t)NQKV * HIDD * 2;
    _Float16* wob   = (_Float16*)ws;                 ws += (size_t)HIDD * HIDD * 2;
    float*    qkvp  = (float*)ws;                    ws += (size_t)2 * SS * NQKV * 4;   // split-K partials (reused for O-proj)
    _Float16* Qhd   = (_Float16*)ws;                 ws += (size_t)HH * SS * DD * 2;
    _Float16* Khd   = (_Float16*)ws;                 ws += (size_t)KVHH * SS * DD * 2;
    _Float16* Vhd   = (_Float16*)ws;                 ws += (size_t)KVHH * SS * DD * 2;
    _Float16* Vtd   = (_Float16*)ws;                 ws += (size_t)KVHH * SS * DD * 2;
    _Float16* attnb = (_Float16*)ws;                 ws += (size_t)SS * HIDD * 2;

    cvt_all<<<12480, 256, 0, stream>>>(hs, Wq, Wk, Wv, Wo, hsb, wqkvb, wob, qa, ka, va, oa);

    // fused QKV projection, split-K=2: partials [2][2048][2688]
    gemm_bt_f16<<<dim3(NQKV / 128, SS / 128, 2), 256, 0, stream>>>(hsb, wqkvb, qkvp, SS, NQKV, HIDD);

    lnrope2<<<(SS * 42) / 4, 256, 0, stream>>>(qkvp, qkvp + (size_t)SS * NQKV, qlnw, klnw, Qhd, Khd, Vhd);

    transpose_v<<<dim3(SS / 64, KVHH), 256, 0, stream>>>(Vhd, Vtd);

    attn_mfma<<<dim3(SS / 64, HH), 256, 0, stream>>>(Qhd, Khd, Vtd, attnb);

    // output projection, split-K=2: partials reuse the (dead) QKV partial region
    float* op = qkvp;
    gemm_bt_f16<<<dim3(HIDD / 128, SS / 128, 2), 256, 0, stream>>>(attnb, wob, op, SS, HIDD, HIDD);
    add2_f32<<<(SS * HIDD) / 1024, 256, 0, stream>>>(op, op + (size_t)SS * HIDD, (float*)d_out);
}

// Round 5
// 146.359 us; speedup vs baseline: 7.0385x; 1.0286x over previous
//
#include <hip/hip_runtime.h>
#include <hip/hip_fp16.h>

#define SS 2048
#define HH 30
#define KVHH 6
#define DD 64
#define HIDD 1920
#define NQKV 2688   // 1920 (q) + 384 (k) + 384 (v)

typedef __attribute__((ext_vector_type(4))) float  f32x4;
typedef __attribute__((ext_vector_type(4))) float  float4v;
typedef __attribute__((ext_vector_type(8))) _Float16 f16x8;
typedef __attribute__((ext_vector_type(4))) _Float16 f16x4;

// ---------------------------------------------------------------- fused f32->f16 cvt (*alpha), 5 regions, 1024 elems/block
__global__ __launch_bounds__(256) void cvt_all(const float* __restrict__ hs,
                                               const float* __restrict__ Wq,
                                               const float* __restrict__ Wk,
                                               const float* __restrict__ Wv,
                                               const float* __restrict__ Wo,
                                               _Float16* __restrict__ hsb,
                                               _Float16* __restrict__ wqkvb,
                                               _Float16* __restrict__ wob,
                                               const float* __restrict__ qa,
                                               const float* __restrict__ ka,
                                               const float* __restrict__ va,
                                               const float* __restrict__ oa) {
    int b = blockIdx.x;
    const float* in; _Float16* out; float a; int base;
    if (b < 3840)      { in = hs; out = hsb;              a = 1.0f;  base = b; }
    else if (b < 7440) { in = Wq; out = wqkvb;            a = qa[0]; base = b - 3840; }
    else if (b < 8160) { in = Wk; out = wqkvb + 3686400;  a = ka[0]; base = b - 7440; }
    else if (b < 8880) { in = Wv; out = wqkvb + 4423680;  a = va[0]; base = b - 8160; }
    else               { in = Wo; out = wob;              a = oa[0]; base = b - 8880; }
    int i = base * 1024 + threadIdx.x * 4;
    float4v v = *(const float4v*)(in + i);
    f16x4 o;
    o[0] = (_Float16)(v[0] * a);
    o[1] = (_Float16)(v[1] * a);
    o[2] = (_Float16)(v[2] * a);
    o[3] = (_Float16)(v[3] * a);
    *(f16x4*)(out + i) = o;
}

// ---------------------------------------------------------------- GEMM: C[M][N] = A[M][K] * B[N][K]^T
// 128x128 tile, BK=64, 4 waves. 2-phase double-buffered K-loop: stage tile t+1
// before computing tile t; ONE barrier per K-step (T3-minimal). XCD swizzle on
// the flattened bid (nwg % 8 == 0 for all grids used here).
#define GEMM_STAGE(buf, ktv)                                                                           \
    do {                                                                                               \
        _Pragma("unroll")                                                                              \
        for (int it = 0; it < 4; ++it) {                                                               \
            int gg  = it * 256 + tid;                                                                  \
            int row = gg >> 3;                                                                         \
            int sl  = (gg & 7) ^ (row & 7);                                                            \
            const _Float16* gA = A + (size_t)(m0 + row) * K + (ktv) + sl * 8;                          \
            const _Float16* gB = B + (size_t)(n0 + row) * K + (ktv) + sl * 8;                          \
            _Float16* lA = As[buf] + (size_t)(it * 256 + w * 64) * 8;                                  \
            _Float16* lB = Bs[buf] + (size_t)(it * 256 + w * 64) * 8;                                  \
            __builtin_amdgcn_global_load_lds((const __attribute__((address_space(1))) unsigned int*)gA,\
                                             (__attribute__((address_space(3))) unsigned int*)lA, 16, 0, 0); \
            __builtin_amdgcn_global_load_lds((const __attribute__((address_space(1))) unsigned int*)gB,\
                                             (__attribute__((address_space(3))) unsigned int*)lB, 16, 0, 0); \
        }                                                                                              \
    } while (0)

__global__ __launch_bounds__(256) void gemm_bt_f16(const _Float16* __restrict__ A,
                                                   const _Float16* __restrict__ B,
                                                   float* __restrict__ C,
                                                   int M, int N, int K) {
    __shared__ __align__(16) _Float16 As[2][128 * 64];
    __shared__ __align__(16) _Float16 Bs[2][128 * 64];
    const int tid = threadIdx.x;
    const int l   = tid & 63;
    const int w   = tid >> 6;
    const int wm  = (w >> 1) * 64;
    const int wn  = (w & 1) * 64;

    // XCD swizzle: consecutive logical tiles (same A panel) -> same XCD L2
    const int gx  = gridDim.x;
    const int nwg = gx * gridDim.y;
    int bid = blockIdx.y * gx + blockIdx.x;
    int lid = (bid & 7) * (nwg >> 3) + (bid >> 3);
    int by  = lid / gx;
    int bx  = lid - by * gx;

    const int m0 = by * 128;
    const int n0 = bx * 128;

    f32x4 acc[4][4];
#pragma unroll
    for (int a = 0; a < 4; ++a)
#pragma unroll
        for (int b = 0; b < 4; ++b) acc[a][b] = (f32x4)0.0f;

    GEMM_STAGE(0, 0);
    __syncthreads();

    const int nk = K >> 6;
    for (int t = 0; t < nk; ++t) {
        const int cur = t & 1;
        if (t + 1 < nk) GEMM_STAGE(cur ^ 1, (t + 1) * 64);   // prefetch flies under compute

#pragma unroll
        for (int kk = 0; kk < 2; ++kk) {
            f16x8 af[4], bf[4];
#pragma unroll
            for (int fm = 0; fm < 4; ++fm) {
                int row = wm + fm * 16 + (l & 15);
                int s   = (kk * 4 + (l >> 4)) ^ (row & 7);
                af[fm] = *(const f16x8*)(As[cur] + row * 64 + s * 8);
            }
#pragma unroll
            for (int fn = 0; fn < 4; ++fn) {
                int row = wn + fn * 16 + (l & 15);
                int s   = (kk * 4 + (l >> 4)) ^ (row & 7);
                bf[fn] = *(const f16x8*)(Bs[cur] + row * 64 + s * 8);
            }
#pragma unroll
            for (int fm = 0; fm < 4; ++fm)
#pragma unroll
                for (int fn = 0; fn < 4; ++fn)
                    acc[fm][fn] = __builtin_amdgcn_mfma_f32_16x16x32_f16(af[fm], bf[fn], acc[fm][fn], 0, 0, 0);
        }
        __syncthreads();   // protects re-staged buffer + drains prefetch
    }

#pragma unroll
    for (int fm = 0; fm < 4; ++fm)
#pragma unroll
        for (int fn = 0; fn < 4; ++fn)
#pragma unroll
            for (int j = 0; j < 4; ++j) {
                int r = m0 + wm + fm * 16 + (l >> 4) * 4 + j;
                int c = n0 + wn + fn * 16 + (l & 15);
                C[(size_t)r * N + c] = acc[fm][fn][j];
            }
}

// ---------------------------------------------------------------- per-head LN + RoPE + reformat
__global__ __launch_bounds__(256) void lnrope(const float* __restrict__ qkv,
                                              const float* __restrict__ qlnw,
                                              const float* __restrict__ klnw,
                                              _Float16* __restrict__ Qh,
                                              _Float16* __restrict__ Kh,
                                              _Float16* __restrict__ Vh) {
    int task = blockIdx.x * 4 + (threadIdx.x >> 6);
    int lane = threadIdx.x & 63;
    int s = task / 42;
    int u = task % 42;
    if (s >= SS) return;

    if (u < 36) {
        int head  = (u < 30) ? u : (u - 30);
        int col   = (u < 30) ? (u * 64 + lane) : (1920 + head * 64 + lane);
        const float* lw = (u < 30) ? qlnw : klnw;
        float x = qkv[(size_t)s * NQKV + col];

        float mu = x;
#pragma unroll
        for (int off = 32; off; off >>= 1) mu += __shfl_xor(mu, off);
        mu *= (1.0f / 64.0f);
        float d = x - mu;
        float var = d * d;
#pragma unroll
        for (int off = 32; off; off >>= 1) var += __shfl_xor(var, off);
        var *= (1.0f / 64.0f);
        float xn = d * rsqrtf(var + 1e-5f) * lw[head * 64 + lane];

        float f = exp2f(-13.287712379549449f * (float)(lane & 31) * (1.0f / 32.0f));
        float ang = (float)s * f;
        float sn, cs;
        sincosf(ang, &sn, &cs);
        float prt = __shfl_xor(xn, 32);
        float rot = (lane < 32) ? -prt : prt;
        float r = xn * cs + rot * sn;

        if (u < 30) Qh[((size_t)head * SS + s) * 64 + lane] = (_Float16)(r * 0.125f);
        else        Kh[((size_t)head * SS + s) * 64 + lane] = (_Float16)r;
    } else {
        int head = u - 36;
        float x = qkv[(size_t)s * NQKV + 2304 + head * 64 + lane];
        Vh[((size_t)head * SS + s) * 64 + lane] = (_Float16)x;
    }
}

// ---------------------------------------------------------------- V transpose: Vh[h][s][d] -> Vt[h][d][s]
__global__ __launch_bounds__(256) void transpose_v(const _Float16* __restrict__ Vh,
                                                   _Float16* __restrict__ Vt) {
    __shared__ _Float16 T[64][68];
    const int s0 = blockIdx.x * 64;
    const int h  = blockIdx.y;
    const int tid = threadIdx.x;
#pragma unroll
    for (int pass = 0; pass < 2; ++pass) {
        int idx = pass * 256 + tid;
        int r = idx >> 3, d0 = (idx & 7) * 8;
        f16x8 v = *(const f16x8*)(Vh + ((size_t)(h * SS + s0 + r)) * 64 + d0);
#pragma unroll
        for (int j = 0; j < 8; ++j) T[r][d0 + j] = v[j];
    }
    __syncthreads();
#pragma unroll
    for (int pass = 0; pass < 2; ++pass) {
        int idx = pass * 256 + tid;
        int d = idx >> 3, c0 = (idx & 7) * 8;
        f16x8 o;
#pragma unroll
        for (int j = 0; j < 8; ++j) o[j] = T[c0 + j][d];
        *(f16x8*)(Vt + ((size_t)(h * 64 + d)) * SS + s0 + c0) = o;
    }
}

// ---------------------------------------------------------------- MFMA sliding-window attention
#define ATTN_STAGE(buf, c)                                                                             \
    do {                                                                                               \
        _Pragma("unroll")                                                                              \
        for (int t = 0; t < 2; ++t) {                                                                  \
            int rloc = w * 16 + t * 8 + (l >> 3);                                                      \
            int ss = (l & 7) ^ (l >> 3);                                                               \
            const _Float16* gK = Kh + ((size_t)kvh * SS + (c) * 64 + rloc) * 64 + ss * 8;              \
            const _Float16* gV = Vt + ((size_t)kvh * 64 + rloc) * SS + (c) * 64 + ss * 8;              \
            _Float16* lK = Ks[buf] + (w * 16 + t * 8) * 64;                                            \
            _Float16* lV = Vs[buf] + (w * 16 + t * 8) * 64;                                            \
            __builtin_amdgcn_global_load_lds((const __attribute__((address_space(1))) unsigned int*)gK,\
                                             (__attribute__((address_space(3))) unsigned int*)lK, 16, 0, 0); \
            __builtin_amdgcn_global_load_lds((const __attribute__((address_space(1))) unsigned int*)gV,\
                                             (__attribute__((address_space(3))) unsigned int*)lV, 16, 0, 0); \
        }                                                                                              \
    } while (0)

__global__ __launch_bounds__(256) void attn_mfma(const _Float16* __restrict__ Qh,
                                                 const _Float16* __restrict__ Kh,
                                                 const _Float16* __restrict__ Vt,
                                                 _Float16* __restrict__ Ob) {
    __shared__ __align__(16) _Float16 Ks[2][64 * 64];
    __shared__ __align__(16) _Float16 Vs[2][64 * 64];
    __shared__ __align__(16) _Float16 Ps[4][16 * 64];

    const int qb = 31 - blockIdx.x;
    const int h = blockIdx.y;
    const int Q0 = qb * 64;
    const int kvh = h / 5;
    const int tid = threadIdx.x, l = tid & 63, w = tid >> 6;
    const int g = l >> 4, li = l & 15;
    const int qabs = Q0 + w * 16 + li;

    f16x8 qf[2];
#pragma unroll
    for (int dk = 0; dk < 2; ++dk)
        qf[dk] = *(const f16x8*)(Qh + ((size_t)h * SS + qabs) * 64 + dk * 32 + g * 8);

    float m_i = -1e20f, l_i = 0.0f;
    f32x4 o[4];
#pragma unroll
    for (int fn = 0; fn < 4; ++fn) o[fn] = (f32x4)0.0f;

    const int c_lo = (Q0 >= 1023) ? ((Q0 - 1023) >> 6) : 0;
    const int c_hi = qb;
    const int qw = Q0 + w * 16;

    ATTN_STAGE(0, c_lo);
    __syncthreads();

    for (int c = c_lo; c <= c_hi; ++c) {
        const int nb = (c - c_lo) & 1;
        if (c < c_hi) ATTN_STAGE(nb ^ 1, c + 1);

        if (c * 64 <= qw + 15 && c * 64 + 63 >= qw - 1023) {
            const _Float16* Kb = Ks[nb];
            const _Float16* Vb = Vs[nb];
            const bool full = (c * 64 + 63 <= qw) && (c * 64 >= qw + 15 - 1023);

            f32x4 st[4];
#pragma unroll
            for (int f = 0; f < 4; ++f) st[f] = (f32x4)0.0f;
            __builtin_amdgcn_s_setprio(1);
#pragma unroll
            for (int dk = 0; dk < 2; ++dk) {
#pragma unroll
                for (int f = 0; f < 4; ++f) {
                    int ps = (dk * 4 + g) ^ (li & 7);
                    f16x8 kf = *(const f16x8*)(Kb + (f * 16 + li) * 64 + ps * 8);
                    st[f] = __builtin_amdgcn_mfma_f32_16x16x32_f16(kf, qf[dk], st[f], 0, 0, 0);
                }
            }
            __builtin_amdgcn_s_setprio(0);

            if (!full) {
#pragma unroll
                for (int f = 0; f < 4; ++f)
#pragma unroll
                    for (int reg = 0; reg < 4; ++reg) {
                        int kab = c * 64 + f * 16 + g * 4 + reg;
                        bool valid = (kab <= qabs) && (qabs - kab < 1024);
                        st[f][reg] = valid ? st[f][reg] : -1e30f;
                    }
            }
            float mx = -1e30f;
#pragma unroll
            for (int f = 0; f < 4; ++f)
#pragma unroll
                for (int reg = 0; reg < 4; ++reg) mx = fmaxf(mx, st[f][reg]);
            mx = fmaxf(mx, __shfl_xor(mx, 16));
            mx = fmaxf(mx, __shfl_xor(mx, 32));

            if (__any(mx > m_i + 6.0f)) {
                float m_new = fmaxf(m_i, mx);
                float corr = __expf(m_i - m_new);
                m_i = m_new;
                l_i *= corr;
                float c0 = __shfl(corr, g * 4 + 0);
                float c1 = __shfl(corr, g * 4 + 1);
                float c2 = __shfl(corr, g * 4 + 2);
                float c3 = __shfl(corr, g * 4 + 3);
#pragma unroll
                for (int fn = 0; fn < 4; ++fn) {
                    o[fn][0] *= c0; o[fn][1] *= c1; o[fn][2] *= c2; o[fn][3] *= c3;
                }
            }

            float psum = 0.0f;
            char* Pw = (char*)&Ps[w][0] + li * 128;
#pragma unroll
            for (int f = 0; f < 4; ++f)
#pragma unroll
                for (int rp = 0; rp < 2; ++rp) {
                    float p0 = __expf(st[f][2 * rp]     - m_i);
                    float p1 = __expf(st[f][2 * rp + 1] - m_i);
                    psum += p0 + p1;
                    union { _Float16 hh[2]; unsigned u; } pk;
                    pk.hh[0] = (_Float16)p0; pk.hh[1] = (_Float16)p1;
                    int phys = (f * 2 + (g >> 1)) ^ (li & 7);
                    *(unsigned*)(Pw + phys * 16 + (g & 1) * 8 + rp * 4) = pk.u;
                }
            psum += __shfl_xor(psum, 16);
            psum += __shfl_xor(psum, 32);
            l_i += psum;

            __builtin_amdgcn_s_setprio(1);
#pragma unroll
            for (int kk = 0; kk < 2; ++kk) {
                int pp = (kk * 4 + g) ^ (li & 7);
                f16x8 pa = *(const f16x8*)(Pw + pp * 16);
#pragma unroll
                for (int fn = 0; fn < 4; ++fn) {
                    int drow = fn * 16 + li;
                    int vp = (kk * 4 + g) ^ (li & 7);
                    f16x8 vf = *(const f16x8*)(Vb + drow * 64 + vp * 8);
                    o[fn] = __builtin_amdgcn_mfma_f32_16x16x32_f16(pa, vf, o[fn], 0, 0, 0);
                }
            }
            __builtin_amdgcn_s_setprio(0);
        }
        __syncthreads();
    }

#pragma unroll
    for (int reg = 0; reg < 4; ++reg) {
        float linv = 1.0f / __shfl(l_i, g * 4 + reg);
        int row = Q0 + w * 16 + g * 4 + reg;
#pragma unroll
        for (int fn = 0; fn < 4; ++fn)
            Ob[(size_t)row * HIDD + h * 64 + fn * 16 + li] = (_Float16)(o[fn][reg] * linv);
    }
}

// ---------------------------------------------------------------- launch
extern "C" void kernel_launch(void* const* d_in, const int* in_sizes, int n_in,
                              void* d_out, int out_size, void* d_ws, size_t ws_size,
                              hipStream_t stream) {
    const float* hs   = (const float*)d_in[0];
    const float* Wq   = (const float*)d_in[2];
    const float* Wk   = (const float*)d_in[3];
    const float* Wv   = (const float*)d_in[4];
    const float* Wo   = (const float*)d_in[5];
    const float* qlnw = (const float*)d_in[6];
    const float* klnw = (const float*)d_in[7];
    const float* qa   = (const float*)d_in[8];
    const float* ka   = (const float*)d_in[9];
    const float* va   = (const float*)d_in[10];
    const float* oa   = (const float*)d_in[11];

    char* ws = (char*)d_ws;
    _Float16* hsb   = (_Float16*)ws;                 ws += (size_t)SS * HIDD * 2;
    _Float16* wqkvb = (_Float16*)ws;                 ws += (size_t)NQKV * HIDD * 2;
    _Float16* wob   = (_Float16*)ws;                 ws += (size_t)HIDD * HIDD * 2;
    float*    qkv   = (float*)ws;                    ws += (size_t)SS * NQKV * 4;
    _Float16* Qhd   = (_Float16*)ws;                 ws += (size_t)HH * SS * DD * 2;
    _Float16* Khd   = (_Float16*)ws;                 ws += (size_t)KVHH * SS * DD * 2;
    _Float16* Vhd   = (_Float16*)ws;                 ws += (size_t)KVHH * SS * DD * 2;
    _Float16* Vtd   = (_Float16*)ws;                 ws += (size_t)KVHH * SS * DD * 2;
    _Float16* attnb = (_Float16*)ws;                 ws += (size_t)SS * HIDD * 2;

    cvt_all<<<12480, 256, 0, stream>>>(hs, Wq, Wk, Wv, Wo, hsb, wqkvb, wob, qa, ka, va, oa);

    // fused QKV projection: [2048,2688] = hs[2048,1920] @ Wqkv[2688,1920]^T
    gemm_bt_f16<<<dim3(NQKV / 128, SS / 128), 256, 0, stream>>>(hsb, wqkvb, qkv, SS, NQKV, HIDD);

    lnrope<<<(SS * 42) / 4, 256, 0, stream>>>(qkv, qlnw, klnw, Qhd, Khd, Vhd);

    transpose_v<<<dim3(SS / 64, KVHH), 256, 0, stream>>>(Vhd, Vtd);

    attn_mfma<<<dim3(SS / 64, HH), 256, 0, stream>>>(Qhd, Khd, Vtd, attnb);

    // output projection: [2048,1920] = attnb @ Wo[1920,1920]^T
    gemm_bt_f16<<<dim3(HIDD / 128, SS / 128), 256, 0, stream>>>(attnb, wob, (float*)d_out, SS, HIDD, HIDD);
}